// Round 2
// baseline (1353.503 us; speedup 1.0000x reference)
//
#include <hip/hip_runtime.h>
#include <hip/hip_bf16.h>

#define NTOK 4096   // B*S
#define HD   1024   // hidden
#define ID   4096   // intermediate
#define NE   8      // experts

typedef float  floatx4 __attribute__((ext_vector_type(4)));
typedef __bf16 bf16x8  __attribute__((ext_vector_type(8)));
typedef unsigned short u16;

__device__ __forceinline__ u16 f2bf(float f) {
    union { float f; unsigned int i; } c; c.f = f;
    return (u16)((c.i + 0x7fffu + ((c.i >> 16) & 1u)) >> 16);   // RNE
}

// async global->LDS, 16B per lane; lds must be the wave-uniform chunk base
__device__ __forceinline__ void async_copy16(u16* lds, const u16* g) {
    __builtin_amdgcn_global_load_lds(
        (const __attribute__((address_space(1))) void*)g,
        (__attribute__((address_space(3))) void*)lds, 16, 0, 0);
}

// ---------------- fp32 -> bf16 conversion (8 elems/thread) ----------------
__global__ __launch_bounds__(256) void convert_kernel(
    const float* __restrict__ src, u16* __restrict__ dst)
{
    const size_t i = ((size_t)blockIdx.x * 256 + threadIdx.x) * 8;
    const float4 a = *(const float4*)(src + i);
    const float4 b = *(const float4*)(src + i + 4);
    ushort4 o0, o1;
    o0.x = f2bf(a.x); o0.y = f2bf(a.y); o0.z = f2bf(a.z); o0.w = f2bf(a.w);
    o1.x = f2bf(b.x); o1.y = f2bf(b.y); o1.z = f2bf(b.z); o1.w = f2bf(b.w);
    *(ushort4*)(dst + i)     = o0;
    *(ushort4*)(dst + i + 4) = o1;
}

// ---------------- router: logits -> softmax -> sort desc -> w[rank][n] ----
__global__ __launch_bounds__(256) void router_kernel(
    const float* __restrict__ x, const float* __restrict__ Wr,
    float* __restrict__ wbuf)
{
    const int n    = blockIdx.x * 4 + (threadIdx.x >> 6);
    const int lane = threadIdx.x & 63;
    const float* xr = x + (size_t)n * HD;
    float acc[NE];
#pragma unroll
    for (int e = 0; e < NE; ++e) acc[e] = 0.f;
    for (int h = lane; h < HD; h += 64) {
        const float xv = xr[h];
#pragma unroll
        for (int e = 0; e < NE; ++e) acc[e] += xv * Wr[e * HD + h];
    }
#pragma unroll
    for (int e = 0; e < NE; ++e) {
        float v = acc[e];
#pragma unroll
        for (int off = 32; off > 0; off >>= 1) v += __shfl_xor(v, off, 64);
        acc[e] = v;
    }
    float mx = acc[0];
#pragma unroll
    for (int e = 1; e < NE; ++e) mx = fmaxf(mx, acc[e]);
    float s = 0.f;
#pragma unroll
    for (int e = 0; e < NE; ++e) { acc[e] = __expf(acc[e] - mx); s += acc[e]; }
    const float inv = 1.f / s;
#pragma unroll
    for (int e = 0; e < NE; ++e) acc[e] *= inv;
    // bubble sort descending (8 elems, fully unrolled, register-resident)
#pragma unroll
    for (int i = 0; i < NE - 1; ++i)
#pragma unroll
        for (int j = 0; j < NE - 1 - i; ++j) {
            const float a = acc[j], b = acc[j + 1];
            acc[j] = fmaxf(a, b); acc[j + 1] = fminf(a, b);
        }
    if (lane < NE) wbuf[lane * NTOK + n] = acc[lane];
}

// ---------------- shared 128x128 BK=32 bf16 MFMA main loop (m97 structure) -
// A: row-major (rows x ld), B: row-major (cols x ld) i.e. B^T input.
__device__ __forceinline__ void gemm_tile(
    const u16* __restrict__ A, const u16* __restrict__ B,
    int ld, int kb, int ke, int rowBase, int colBase,
    u16* As, u16* Bs, floatx4 acc[4][4])
{
    const int t    = threadIdx.x;
    const int w    = t >> 6;
    const int lane = t & 63;
    const int wm   = w & 1, wn = w >> 1;
    const int quad = lane >> 4, l15 = lane & 15;
    const int srow = lane >> 2;          // 0..15 (staging row within wave chunk)
    const int scol = (lane & 3) << 3;    // 0/8/16/24

    const u16* gA = A + (size_t)(rowBase + w * 16 + srow) * ld + kb + scol;
    const u16* gB = B + (size_t)(colBase + w * 16 + srow) * ld + kb + scol;
    u16* ldsA = As + w * 512;            // wave-uniform 1KB chunk base
    u16* ldsB = Bs + w * 512;
    const size_t rstep = (size_t)64 * ld;

    int aoff[4], boff[4];
#pragma unroll
    for (int i = 0; i < 4; ++i) {
        aoff[i] = (wm * 64 + i * 16 + l15) * 32 + quad * 8;
        boff[i] = (wn * 64 + i * 16 + l15) * 32 + quad * 8;
    }

    for (int k0 = kb; k0 < ke; k0 += 32) {
        async_copy16(ldsA,        gA);
        async_copy16(ldsA + 2048, gA + rstep);
        async_copy16(ldsB,        gB);
        async_copy16(ldsB + 2048, gB + rstep);
        gA += 32; gB += 32;
        __syncthreads();                 // drains vmcnt for global_load_lds
        bf16x8 af[4], bfr[4];
#pragma unroll
        for (int i = 0; i < 4; ++i) {
            af[i]  = *(const bf16x8*)(As + aoff[i]);
            bfr[i] = *(const bf16x8*)(Bs + boff[i]);
        }
#pragma unroll
        for (int mi = 0; mi < 4; ++mi)
#pragma unroll
            for (int ni = 0; ni < 4; ++ni)
                acc[mi][ni] = __builtin_amdgcn_mfma_f32_16x16x32_bf16(
                    af[mi], bfr[ni], acc[mi][ni], 0, 0, 0);
        __syncthreads();                 // LDS reuse guard
    }
}

// ---------------- GEMM1: hmid = gelu(X @ W1e^T), bf16 out ------------------
__global__ __launch_bounds__(256) void gemm1_kernel(
    const u16* __restrict__ X, const u16* __restrict__ W1e,
    u16* __restrict__ hmid)
{
    __shared__ __align__(16) u16 As[128 * 32];
    __shared__ __align__(16) u16 Bs[128 * 32];
    floatx4 acc[4][4] = {};
    const int rowBase = blockIdx.y * 128, colBase = blockIdx.x * 128;
    gemm_tile(X, W1e, HD, 0, HD, rowBase, colBase, As, Bs, acc);

    const int t = threadIdx.x, w = t >> 6, lane = t & 63;
    const int wm = w & 1, wn = w >> 1, quad = lane >> 4, l15 = lane & 15;
#pragma unroll
    for (int mi = 0; mi < 4; ++mi)
#pragma unroll
        for (int r = 0; r < 4; ++r) {
            const int row = rowBase + wm * 64 + mi * 16 + quad * 4 + r;
#pragma unroll
            for (int ni = 0; ni < 4; ++ni) {
                const int col = colBase + wn * 64 + ni * 16 + l15;
                float v = acc[mi][ni][r];
                v = 0.5f * v * (1.f + erff(v * 0.70710678118f));  // exact GELU
                hmid[(size_t)row * ID + col] = f2bf(v);
            }
        }
}

// ---------------- GEMM2: acc[z] (+)= w[n] * (hmid @ W2e^T), fp32 ----------
__global__ __launch_bounds__(256) void gemm2_kernel(
    const u16* __restrict__ hmid, const u16* __restrict__ W2e,
    const float* __restrict__ wexp, float* __restrict__ accbuf, int init)
{
    __shared__ __align__(16) u16 As[128 * 32];
    __shared__ __align__(16) u16 Bs[128 * 32];
    floatx4 acc[4][4] = {};
    const int rowBase = blockIdx.y * 128, colBase = blockIdx.x * 128;
    const int z = blockIdx.z;
    const int kb = z * (ID / 2), ke = kb + (ID / 2);
    gemm_tile(hmid, W2e, ID, kb, ke, rowBase, colBase, As, Bs, acc);

    float* accs = accbuf + (size_t)z * NTOK * HD;
    const int t = threadIdx.x, w = t >> 6, lane = t & 63;
    const int wm = w & 1, wn = w >> 1, quad = lane >> 4, l15 = lane & 15;
#pragma unroll
    for (int mi = 0; mi < 4; ++mi)
#pragma unroll
        for (int r = 0; r < 4; ++r) {
            const int row = rowBase + wm * 64 + mi * 16 + quad * 4 + r;
            const float wv = wexp[row];
#pragma unroll
            for (int ni = 0; ni < 4; ++ni) {
                const int col = colBase + wn * 64 + ni * 16 + l15;
                const size_t idx = (size_t)row * HD + col;
                const float v = wv * acc[mi][ni][r];
                if (init) accs[idx] = v; else accs[idx] += v;
            }
        }
}

// ---------------- finalize: out = acc[0] + acc[1] (fp32) ------------------
__global__ __launch_bounds__(256) void finalize_kernel(
    const float* __restrict__ accbuf, float* __restrict__ out)
{
    const size_t NH = (size_t)NTOK * HD;
    const size_t i = ((size_t)blockIdx.x * 256 + threadIdx.x) * 4;
    const float4 a = *(const float4*)(accbuf + i);
    const float4 b = *(const float4*)(accbuf + NH + i);
    float4 o;
    o.x = a.x + b.x; o.y = a.y + b.y; o.z = a.z + b.z; o.w = a.w + b.w;
    *(float4*)(out + i) = o;
}

extern "C" void kernel_launch(void* const* d_in, const int* in_sizes, int n_in,
                              void* d_out, int out_size, void* d_ws, size_t ws_size,
                              hipStream_t stream) {
    const float* x  = (const float*)d_in[0];   // (N, H) fp32
    const float* Wr = (const float*)d_in[1];   // (E, H) fp32
    const float* W1 = (const float*)d_in[2];   // (E, I, H) fp32
    const float* W2 = (const float*)d_in[3];   // (E, H, I) fp32
    float* out = (float*)d_out;                // (N, H) fp32

    // ws layout (bytes):
    //   wbuf   @ 0         : E*N f32            = 128 KB
    //   Xb     @ 131072    : N*H bf16           = 8 MB
    //   W1eb   @ +8MB      : I*H bf16           = 8 MB   (per-expert, reused)
    //   W2eb   @ +8MB      : H*I bf16           = 8 MB   (per-expert, reused)
    //   hmid   @ +8MB      : N*I bf16           = 32 MB
    //   accbuf @ +32MB     : 2*N*H f32          = 32 MB
    // total ~88.1 MB
    char* ws = (char*)d_ws;
    float* wbuf   = (float*)ws;
    u16*   Xb     = (u16*)(ws + 131072);
    u16*   W1eb   = (u16*)(ws + 131072 + (size_t)8 * 1024 * 1024);
    u16*   W2eb   = (u16*)(ws + 131072 + (size_t)16 * 1024 * 1024);
    u16*   hmid   = (u16*)(ws + 131072 + (size_t)24 * 1024 * 1024);
    float* accbuf = (float*)(ws + 131072 + (size_t)56 * 1024 * 1024);

    const int convGrid = (NTOK * HD) / (256 * 8);        // 4M elems -> 2048 blocks
    convert_kernel<<<dim3(convGrid), 256, 0, stream>>>(x, Xb);
    router_kernel<<<dim3(NTOK / 4), 256, 0, stream>>>(x, Wr, wbuf);

    for (int e = 0; e < NE; ++e) {
        convert_kernel<<<dim3(convGrid), 256, 0, stream>>>(
            W1 + (size_t)e * ID * HD, W1eb);
        gemm1_kernel<<<dim3(ID / 128, NTOK / 128), 256, 0, stream>>>(
            Xb, W1eb, hmid);
        convert_kernel<<<dim3(convGrid), 256, 0, stream>>>(
            W2 + (size_t)e * HD * ID, W2eb);
        gemm2_kernel<<<dim3(HD / 128, NTOK / 128, 2), 256, 0, stream>>>(
            hmid, W2eb, wbuf + (size_t)e * NTOK, accbuf, e == 0);
    }
    finalize_kernel<<<dim3(NTOK * HD / 1024), 256, 0, stream>>>(accbuf, out);
}

// Round 3
// 1167.027 us; speedup vs baseline: 1.1598x; 1.1598x over previous
//
#include <hip/hip_runtime.h>
#include <hip/hip_bf16.h>

#define NTOK 4096   // B*S tokens
#define HD   1024   // hidden
#define ID   4096   // intermediate
#define NE   8      // experts
#define LDH  (NE * ID)   // 32768: hmid leading dim (all experts side by side)

typedef float  floatx4 __attribute__((ext_vector_type(4)));
typedef __bf16 bf16x8  __attribute__((ext_vector_type(8)));
typedef unsigned short u16;

__device__ __forceinline__ u16 f2bf(float f) {
    union { float f; unsigned int i; } c; c.f = f;
    return (u16)((c.i + 0x7fffu + ((c.i >> 16) & 1u)) >> 16);   // RNE
}

// async global->LDS, 16B per lane; lds must be the wave-uniform chunk base
__device__ __forceinline__ void async_copy16(u16* lds, const u16* g) {
    __builtin_amdgcn_global_load_lds(
        (const __attribute__((address_space(1))) void*)g,
        (__attribute__((address_space(3))) void*)lds, 16, 0, 0);
}

// tanh-approx GELU (max abs err ~3e-3; exp-based, ~8 VALU ops vs ~25 for erff)
__device__ __forceinline__ float gelu_fast(float v) {
    const float u = v * (0.7978845608f + 0.0356774081f * v * v);  // sqrt(2/pi)*(v+0.044715v^3)
    const float t = 1.f - 2.f / (__expf(2.f * u) + 1.f);          // tanh(u)
    return 0.5f * v * (1.f + t);
}

// ---------------- fp32 -> bf16 conversion (8 elems/thread) ----------------
__global__ __launch_bounds__(256) void convert_kernel(
    const float* __restrict__ src, u16* __restrict__ dst)
{
    const size_t i = ((size_t)blockIdx.x * 256 + threadIdx.x) * 8;
    const float4 a = *(const float4*)(src + i);
    const float4 b = *(const float4*)(src + i + 4);
    ushort4 o0, o1;
    o0.x = f2bf(a.x); o0.y = f2bf(a.y); o0.z = f2bf(a.z); o0.w = f2bf(a.w);
    o1.x = f2bf(b.x); o1.y = f2bf(b.y); o1.z = f2bf(b.z); o1.w = f2bf(b.w);
    *(ushort4*)(dst + i)     = o0;
    *(ushort4*)(dst + i + 4) = o1;
}

// ---------------- router: logits -> softmax -> sort desc -> w[rank][n] ----
__global__ __launch_bounds__(256) void router_kernel(
    const float* __restrict__ x, const float* __restrict__ Wr,
    float* __restrict__ wbuf)
{
    const int n    = blockIdx.x * 4 + (threadIdx.x >> 6);
    const int lane = threadIdx.x & 63;
    const float* xr = x + (size_t)n * HD;
    float acc[NE];
#pragma unroll
    for (int e = 0; e < NE; ++e) acc[e] = 0.f;
    for (int h = lane; h < HD; h += 64) {
        const float xv = xr[h];
#pragma unroll
        for (int e = 0; e < NE; ++e) acc[e] += xv * Wr[e * HD + h];
    }
#pragma unroll
    for (int e = 0; e < NE; ++e) {
        float v = acc[e];
#pragma unroll
        for (int off = 32; off > 0; off >>= 1) v += __shfl_xor(v, off, 64);
        acc[e] = v;
    }
    float mx = acc[0];
#pragma unroll
    for (int e = 1; e < NE; ++e) mx = fmaxf(mx, acc[e]);
    float s = 0.f;
#pragma unroll
    for (int e = 0; e < NE; ++e) { acc[e] = __expf(acc[e] - mx); s += acc[e]; }
    const float inv = 1.f / s;
#pragma unroll
    for (int e = 0; e < NE; ++e) acc[e] *= inv;
    // bubble sort descending (8 elems, register-resident)
#pragma unroll
    for (int i = 0; i < NE - 1; ++i)
#pragma unroll
        for (int j = 0; j < NE - 1 - i; ++j) {
            const float a = acc[j], b = acc[j + 1];
            acc[j] = fmaxf(a, b); acc[j + 1] = fminf(a, b);
        }
    if (lane < NE) wbuf[lane * NTOK + n] = acc[lane];
}

// ---------------- shared 128x128 BK=32 bf16 MFMA main loop (m97 structure) -
// A: row-major (rows x ldA), B: row-major (cols x ldB) i.e. B^T input.
__device__ __forceinline__ void gemm_tile(
    const u16* __restrict__ A, const u16* __restrict__ B,
    int ldA, int ldB, int kb, int ke, int rowBase, int colBase,
    u16* As, u16* Bs, floatx4 acc[4][4])
{
    const int t    = threadIdx.x;
    const int w    = t >> 6;
    const int lane = t & 63;
    const int wm   = w & 1, wn = w >> 1;
    const int quad = lane >> 4, l15 = lane & 15;
    const int srow = lane >> 2;          // 0..15 (staging row within wave chunk)
    const int scol = (lane & 3) << 3;    // 0/8/16/24

    const u16* gA = A + (size_t)(rowBase + w * 16 + srow) * ldA + kb + scol;
    const u16* gB = B + (size_t)(colBase + w * 16 + srow) * ldB + kb + scol;
    u16* ldsA = As + w * 512;            // wave-uniform 1KB chunk base
    u16* ldsB = Bs + w * 512;
    const size_t rstepA = (size_t)64 * ldA;
    const size_t rstepB = (size_t)64 * ldB;

    int aoff[4], boff[4];
#pragma unroll
    for (int i = 0; i < 4; ++i) {
        aoff[i] = (wm * 64 + i * 16 + l15) * 32 + quad * 8;
        boff[i] = (wn * 64 + i * 16 + l15) * 32 + quad * 8;
    }

    for (int k0 = kb; k0 < ke; k0 += 32) {
        async_copy16(ldsA,         gA);
        async_copy16(ldsA + 2048,  gA + rstepA);
        async_copy16(ldsB,         gB);
        async_copy16(ldsB + 2048,  gB + rstepB);
        gA += 32; gB += 32;
        __syncthreads();                 // drains vmcnt for global_load_lds
        bf16x8 af[4], bfr[4];
#pragma unroll
        for (int i = 0; i < 4; ++i) {
            af[i]  = *(const bf16x8*)(As + aoff[i]);
            bfr[i] = *(const bf16x8*)(Bs + boff[i]);
        }
#pragma unroll
        for (int mi = 0; mi < 4; ++mi)
#pragma unroll
            for (int ni = 0; ni < 4; ++ni)
                acc[mi][ni] = __builtin_amdgcn_mfma_f32_16x16x32_bf16(
                    af[mi], bfr[ni], acc[mi][ni], 0, 0, 0);
        __syncthreads();                 // LDS reuse guard
    }
}

// ------- GEMM1 (all experts): hmid[n, e*I+i] = w[e][n]*gelu(X @ W1^T) -----
// W1 viewed as (E*I, H) row-major = B^T. Router weight folded in (fp32) before
// the bf16 round -> identical math to weighting GEMM2's output.
__global__ __launch_bounds__(256) void gemm1_kernel(
    const u16* __restrict__ X, const u16* __restrict__ W1b,
    const float* __restrict__ wbuf, u16* __restrict__ hmid)
{
    __shared__ __align__(16) u16 As[128 * 32];
    __shared__ __align__(16) u16 Bs[128 * 32];
    floatx4 acc[4][4] = {};
    const int rowBase = blockIdx.y * 128, colBase = blockIdx.x * 128;
    const int e = colBase >> 12;                      // colBase / ID
    gemm_tile(X, W1b, HD, HD, 0, HD, rowBase, colBase, As, Bs, acc);

    const int t = threadIdx.x, w = t >> 6, lane = t & 63;
    const int wm = w & 1, wn = w >> 1, quad = lane >> 4, l15 = lane & 15;
#pragma unroll
    for (int mi = 0; mi < 4; ++mi)
#pragma unroll
        for (int r = 0; r < 4; ++r) {
            const int row = rowBase + wm * 64 + mi * 16 + quad * 4 + r;
            const float wv = wbuf[e * NTOK + row];
#pragma unroll
            for (int ni = 0; ni < 4; ++ni) {
                const int col = colBase + wn * 64 + ni * 16 + l15;
                const float v = gelu_fast(acc[mi][ni][r]);
                hmid[(size_t)row * LDH + col] = f2bf(v * wv);
            }
        }
}

// ------- GEMM2 (expert-pair per z): slice[z] = sum_e hmid_e @ W2_e^T ------
// grid (NTOK/128, HD/128, 4): blockIdx.x = token rows (fastest-varying) so the
// 8 col-blocks sharing one hmid row-stripe land on the SAME XCD (ids = x mod 8
// equal) -> L2 reuse of the 256 MB hmid.
__global__ __launch_bounds__(256) void gemm2_kernel(
    const u16* __restrict__ hmid, const u16* __restrict__ W2b,
    float* __restrict__ accbuf)
{
    __shared__ __align__(16) u16 As[128 * 32];
    __shared__ __align__(16) u16 Bs[128 * 32];
    floatx4 acc[4][4] = {};
    const int rowBase = blockIdx.x * 128;   // tokens
    const int colBase = blockIdx.y * 128;   // hidden
    const int z = blockIdx.z;
    for (int ee = 0; ee < 2; ++ee) {
        const int e = 2 * z + ee;
        gemm_tile(hmid + (size_t)e * ID, W2b + (size_t)e * HD * ID,
                  LDH, ID, 0, ID, rowBase, colBase, As, Bs, acc);
    }

    float* accs = accbuf + (size_t)z * NTOK * HD;
    const int t = threadIdx.x, w = t >> 6, lane = t & 63;
    const int wm = w & 1, wn = w >> 1, quad = lane >> 4, l15 = lane & 15;
#pragma unroll
    for (int mi = 0; mi < 4; ++mi)
#pragma unroll
        for (int r = 0; r < 4; ++r) {
            const int row = rowBase + wm * 64 + mi * 16 + quad * 4 + r;
#pragma unroll
            for (int ni = 0; ni < 4; ++ni) {
                const int col = colBase + wn * 64 + ni * 16 + l15;
                accs[(size_t)row * HD + col] = acc[mi][ni][r];
            }
        }
}

// ---------------- finalize: out = sum of 4 slices (fp32) ------------------
__global__ __launch_bounds__(256) void finalize_kernel(
    const float* __restrict__ accbuf, float* __restrict__ out)
{
    const size_t NH = (size_t)NTOK * HD;
    const size_t i = ((size_t)blockIdx.x * 256 + threadIdx.x) * 4;
    const float4 a = *(const float4*)(accbuf + i);
    const float4 b = *(const float4*)(accbuf + NH + i);
    const float4 c = *(const float4*)(accbuf + 2 * NH + i);
    const float4 d = *(const float4*)(accbuf + 3 * NH + i);
    float4 o;
    o.x = a.x + b.x + c.x + d.x; o.y = a.y + b.y + c.y + d.y;
    o.z = a.z + b.z + c.z + d.z; o.w = a.w + b.w + c.w + d.w;
    *(float4*)(out + i) = o;
}

extern "C" void kernel_launch(void* const* d_in, const int* in_sizes, int n_in,
                              void* d_out, int out_size, void* d_ws, size_t ws_size,
                              hipStream_t stream) {
    const float* x  = (const float*)d_in[0];   // (N, H) fp32
    const float* Wr = (const float*)d_in[1];   // (E, H) fp32
    const float* W1 = (const float*)d_in[2];   // (E, I, H) fp32
    const float* W2 = (const float*)d_in[3];   // (E, H, I) fp32
    float* out = (float*)d_out;                // (N, H) fp32

    // ws layout (bytes):
    //   wbuf   @ 0        : E*N f32        = 128 KB
    //   Xb     @ 128K     : N*H bf16       = 8 MB
    //   W1b    @ +8M      : E*I*H bf16     = 64 MB
    //   W2b    @ +64M     : E*H*I bf16     = 64 MB
    //   hmid   @ +64M     : N*E*I bf16     = 256 MB
    //   accbuf @ +256M    : 4*N*H f32      = 64 MB
    // total ~456.1 MB (observed ws_size = 512 MiB via harness poison fills)
    const size_t MB = 1024 * 1024;
    char* ws = (char*)d_ws;
    float* wbuf   = (float*)ws;
    u16*   Xb     = (u16*)(ws + 131072);
    u16*   W1b    = (u16*)(ws + 131072 + 8 * MB);
    u16*   W2b    = (u16*)(ws + 131072 + 72 * MB);
    u16*   hmid   = (u16*)(ws + 131072 + 136 * MB);
    float* accbuf = (float*)(ws + 131072 + 392 * MB);
    if (ws_size < 131072 + 456 * MB) return;   // fail loudly rather than corrupt

    convert_kernel<<<dim3((NTOK * HD) / 2048), 256, 0, stream>>>(x, Xb);
    convert_kernel<<<dim3((NE * ID * HD) / 2048), 256, 0, stream>>>(W1, W1b);
    convert_kernel<<<dim3((NE * HD * ID) / 2048), 256, 0, stream>>>(W2, W2b);
    router_kernel<<<dim3(NTOK / 4), 256, 0, stream>>>(x, Wr, wbuf);

    gemm1_kernel<<<dim3(NE * ID / 128, NTOK / 128), 256, 0, stream>>>(
        Xb, W1b, wbuf, hmid);
    gemm2_kernel<<<dim3(NTOK / 128, HD / 128, 4), 256, 0, stream>>>(
        hmid, W2b, accbuf);
    finalize_kernel<<<dim3(NTOK * HD / 1024), 256, 0, stream>>>(accbuf, out);
}